// Round 1
// baseline (436.330 us; speedup 1.0000x reference)
//
#include <hip/hip_runtime.h>
#include <hip/hip_bf16.h>

#define B_   256
#define T_   2048
#define D_   100
#define U_   50
#define S_   32
#define SEC_ 64

__device__ __forceinline__ float fast_tanh(float x) {
    // tanh(x) = 1 - 2/(1 + e^{2x}); safe at +-inf (e->inf => 1, e->0 => -1)
    float e = __expf(2.0f * x);
    return 1.0f - 2.0f * __builtin_amdgcn_rcpf(1.0f + e);
}

// wu_proj[b][u] = dot(user_vec[b], wu[u]) + bw[u]
__global__ __launch_bounds__(64) void wu_proj_kernel(
    const float* __restrict__ user_vec, const float* __restrict__ wu,
    const float* __restrict__ bw, float* __restrict__ wup) {
    int b = blockIdx.x;
    int u = threadIdx.x;
    if (u >= U_) return;
    const float4* uv4 = reinterpret_cast<const float4*>(user_vec + b * D_);
    const float4* wu4 = reinterpret_cast<const float4*>(wu + u * D_);
    float acc = 0.f;
#pragma unroll
    for (int c = 0; c < D_ / 4; ++c) {
        float4 a = uv4[c];
        float4 w = wu4[c];
        acc = __builtin_fmaf(a.x, w.x, acc);
        acc = __builtin_fmaf(a.y, w.y, acc);
        acc = __builtin_fmaf(a.z, w.z, acc);
        acc = __builtin_fmaf(a.w, w.w, acc);
    }
    wup[b * U_ + u] = acc + bw[u];
}

// One wave (64 threads) per (b, s) section. Lane = word within section.
__global__ __launch_bounds__(64) void attn_pool_kernel(
    const float* __restrict__ sent,    // [B, T, D]
    const float* __restrict__ vw,      // [U, 1]
    const float* __restrict__ wh,      // [U, D]
    const float* __restrict__ wup_all, // [B, U] (from d_ws)
    float* __restrict__ out) {         // [B, S, D]
    __shared__ float sect[SEC_ * D_];  // 25600 B, natural (unpadded) layout
    __shared__ float alpha_s[SEC_];

    const int s = blockIdx.x;
    const int b = blockIdx.y;
    const int t = threadIdx.x;  // 0..63

    const float* gsec = sent + ((size_t)b * T_ + (size_t)s * SEC_) * D_;

    // ---- stage section into LDS (coalesced float4) ----
    float4* s4 = reinterpret_cast<float4*>(sect);
    const float4* g4 = reinterpret_cast<const float4*>(gsec);
#pragma unroll
    for (int i = 0; i < (SEC_ * D_ / 4) / 64; ++i) {  // 25 iters
        s4[i * 64 + t] = g4[i * 64 + t];
    }
    __syncthreads();

    // ---- projection: acc[u] = dot(word_t, wh[u]) ----
    float acc[U_];
#pragma unroll
    for (int u = 0; u < U_; ++u) acc[u] = 0.f;

    const float4* w4  = reinterpret_cast<const float4*>(wh);  // uniform -> s_load
    const float4* my4 = s4 + t * (D_ / 4);

#pragma unroll 5
    for (int c = 0; c < D_ / 4; ++c) {
        float4 wv = my4[c];
#pragma unroll
        for (int u = 0; u < U_; ++u) {
            float4 h = w4[u * (D_ / 4) + c];
            acc[u] = __builtin_fmaf(wv.x, h.x, acc[u]);
            acc[u] = __builtin_fmaf(wv.y, h.y, acc[u]);
            acc[u] = __builtin_fmaf(wv.z, h.z, acc[u]);
            acc[u] = __builtin_fmaf(wv.w, h.w, acc[u]);
        }
    }

    // ---- e[t] = sum_u vw[u] * tanh(acc[u] + wu_proj[b][u]) ----
    const float* wup = wup_all + b * U_;
    float e = 0.f;
#pragma unroll
    for (int u = 0; u < U_; ++u) {
        e = __builtin_fmaf(vw[u], fast_tanh(acc[u] + wup[u]), e);
    }

    // ---- softmax over the 64 lanes (one value per lane) ----
    float m = e;
#pragma unroll
    for (int off = 32; off > 0; off >>= 1) m = fmaxf(m, __shfl_xor(m, off));
    float p = __expf(e - m);
    float sum = p;
#pragma unroll
    for (int off = 32; off > 0; off >>= 1) sum += __shfl_xor(sum, off);
    float a = p / sum;

    alpha_s[t] = a;
    __syncthreads();

    // ---- weighted sum: out[d] = sum_t alpha[t] * sect[t][d] ----
    // lane covers d = t and d = 64 + t (t < 36)
    float o0 = 0.f, o1 = 0.f;
#pragma unroll 8
    for (int w = 0; w < SEC_; ++w) {
        float aw = alpha_s[w];
        o0 = __builtin_fmaf(aw, sect[w * D_ + t], o0);
        if (t < D_ - SEC_) o1 = __builtin_fmaf(aw, sect[w * D_ + SEC_ + t], o1);
    }
    float* po = out + ((size_t)b * S_ + s) * D_;
    po[t] = o0;
    if (t < D_ - SEC_) po[SEC_ + t] = o1;
}

extern "C" void kernel_launch(void* const* d_in, const int* in_sizes, int n_in,
                              void* d_out, int out_size, void* d_ws, size_t ws_size,
                              hipStream_t stream) {
    const float* sent = (const float*)d_in[0];
    const float* uvec = (const float*)d_in[1];
    const float* vw   = (const float*)d_in[2];
    const float* wh   = (const float*)d_in[3];
    const float* wu   = (const float*)d_in[4];
    const float* bw   = (const float*)d_in[5];
    float* out = (float*)d_out;
    float* wup = (float*)d_ws;  // B_*U_ floats = 51.2 KB

    wu_proj_kernel<<<dim3(B_), dim3(64), 0, stream>>>(uvec, wu, bw, wup);
    attn_pool_kernel<<<dim3(S_, B_), dim3(64), 0, stream>>>(sent, vw, wh, wup, out);
}

// Round 2
// 134.757 us; speedup vs baseline: 3.2379x; 3.2379x over previous
//
#include <hip/hip_runtime.h>
#include <hip/hip_bf16.h>

#define B_   256
#define T_   2048
#define D_   100
#define U_   50
#define S_   32
#define SEC_ 64

typedef __attribute__((ext_vector_type(8))) short short8;
typedef __attribute__((ext_vector_type(4))) float f32x4;

__device__ __forceinline__ float fast_tanh(float x) {
    // tanh(x) = 1 - 2/(1 + e^{2x}); safe at +-inf
    float e = __expf(2.0f * x);
    return 1.0f - 2.0f * __builtin_amdgcn_rcpf(1.0f + e);
}

__device__ __forceinline__ short f2bf(float f) {
    union { __hip_bfloat16 h; unsigned short u; } cv;
    cv.h = __float2bfloat16(f);  // RNE
    return (short)cv.u;
}

// A fragment for mfma_f32_16x16x32_bf16: lane l holds A[l&15][k], with
// k = 32*KS + 4*(l>>4) + i (i=0..3) and k+16 (i=4..7).  Row always valid;
// K padded 100 -> 128 with zeros (only KS==3 partially valid).
template<int KS>
__device__ __forceinline__ short8 frag_a(const float* __restrict__ row, int g) {
    short8 r;
    if constexpr (KS < 3) {
        const int k0 = 32 * KS + 4 * g;
        f32x4 a = *reinterpret_cast<const f32x4*>(row + k0);
        f32x4 b = *reinterpret_cast<const f32x4*>(row + k0 + 16);
        r[0] = f2bf(a[0]); r[1] = f2bf(a[1]); r[2] = f2bf(a[2]); r[3] = f2bf(a[3]);
        r[4] = f2bf(b[0]); r[5] = f2bf(b[1]); r[6] = f2bf(b[2]); r[7] = f2bf(b[3]);
    } else {
        // k = 96 + 4g (+i): valid only for g==0 (k 96..99); k+16 >= 112 all pad
        bool v = (g == 0);
        f32x4 a = *reinterpret_cast<const f32x4*>(row + (v ? 96 : 0));
        float m = v ? 1.f : 0.f;
        r[0] = f2bf(a[0] * m); r[1] = f2bf(a[1] * m);
        r[2] = f2bf(a[2] * m); r[3] = f2bf(a[3] * m);
        r[4] = 0; r[5] = 0; r[6] = 0; r[7] = 0;
    }
    return r;
}

// B fragment: lane l holds Wh^T[k][16n + (l&15)] = Wh[u][k]; same k pattern.
// rv = 0 masks padded units (u >= 50); row pointer pre-clamped in-bounds.
template<int KS>
__device__ __forceinline__ short8 frag_b(const float* __restrict__ row, int g, float rv) {
    short8 r;
    if constexpr (KS < 3) {
        const int k0 = 32 * KS + 4 * g;
        f32x4 a = *reinterpret_cast<const f32x4*>(row + k0);
        f32x4 b = *reinterpret_cast<const f32x4*>(row + k0 + 16);
        r[0] = f2bf(a[0] * rv); r[1] = f2bf(a[1] * rv);
        r[2] = f2bf(a[2] * rv); r[3] = f2bf(a[3] * rv);
        r[4] = f2bf(b[0] * rv); r[5] = f2bf(b[1] * rv);
        r[6] = f2bf(b[2] * rv); r[7] = f2bf(b[3] * rv);
    } else {
        bool v = (g == 0);
        f32x4 a = *reinterpret_cast<const f32x4*>(row + (v ? 96 : 0));
        float m = v ? rv : 0.f;
        r[0] = f2bf(a[0] * m); r[1] = f2bf(a[1] * m);
        r[2] = f2bf(a[2] * m); r[3] = f2bf(a[3] * m);
        r[4] = 0; r[5] = 0; r[6] = 0; r[7] = 0;
    }
    return r;
}

// wu_proj[b][u] = dot(user_vec[b], wu[u]) + bw[u]   (fp32, trivial)
__global__ __launch_bounds__(64) void wu_proj_kernel(
    const float* __restrict__ user_vec, const float* __restrict__ wu,
    const float* __restrict__ bw, float* __restrict__ wup) {
    int b = blockIdx.x;
    int u = threadIdx.x;
    if (u >= U_) return;
    const f32x4* uv4 = reinterpret_cast<const f32x4*>(user_vec + b * D_);
    const f32x4* wu4 = reinterpret_cast<const f32x4*>(wu + u * D_);
    float acc = 0.f;
#pragma unroll
    for (int c = 0; c < D_ / 4; ++c) {
        f32x4 a = uv4[c];
        f32x4 w = wu4[c];
        acc = __builtin_fmaf(a[0], w[0], acc);
        acc = __builtin_fmaf(a[1], w[1], acc);
        acc = __builtin_fmaf(a[2], w[2], acc);
        acc = __builtin_fmaf(a[3], w[3], acc);
    }
    wup[b * U_ + u] = acc + bw[u];
}

// Block = 4 waves; each wave owns one (b, s) section end-to-end.
__global__ __launch_bounds__(256) void attn_pool_mfma(
    const float* __restrict__ sent,     // [B, T, D]
    const float* __restrict__ vw,       // [U]
    const float* __restrict__ wh,       // [U, D]
    const float* __restrict__ wup_all,  // [B, U]
    float* __restrict__ out) {          // [B, S, D]
    __shared__ float alpha_s[4][SEC_];

    const int tid = threadIdx.x;
    const int wid = tid >> 6;
    const int l   = tid & 63;
    const int g   = l >> 4;   // 16-lane group
    const int li  = l & 15;

    const int b = blockIdx.x >> 3;
    const int s = (blockIdx.x & 7) * 4 + wid;

    // ---- persistent B fragments (Wh as bf16), vw / wu_proj slices ----
    short8 bfrag[4][4];  // [n][ks]
    float vwl[4], gl[4];
    const float* wup = wup_all + b * U_;
#pragma unroll
    for (int n = 0; n < 4; ++n) {
        const int uu = 16 * n + li;
        const bool uv = (uu < U_);
        const float rv = uv ? 1.f : 0.f;
        const int uc = uv ? uu : (U_ - 1);
        const float* wrow = wh + uc * D_;
        bfrag[n][0] = frag_b<0>(wrow, g, rv);
        bfrag[n][1] = frag_b<1>(wrow, g, rv);
        bfrag[n][2] = frag_b<2>(wrow, g, rv);
        bfrag[n][3] = frag_b<3>(wrow, g, rv);
        vwl[n] = vw[uc] * rv;
        gl[n]  = wup[uc] * rv;
    }

    const float* secbase = sent + ((size_t)b * T_ + (size_t)s * SEC_) * D_;

    // ---- projection via MFMA + e-scores ----
    float e[4][4];  // [m][r] -> word 16m + 4g + r (replicated across li)
#pragma unroll
    for (int m = 0; m < 4; ++m) {
        const float* arow = secbase + (16 * m + li) * D_;
        short8 af[4];
        af[0] = frag_a<0>(arow, g);
        af[1] = frag_a<1>(arow, g);
        af[2] = frag_a<2>(arow, g);
        af[3] = frag_a<3>(arow, g);

        f32x4 acc[4];
#pragma unroll
        for (int n = 0; n < 4; ++n) acc[n] = (f32x4){0.f, 0.f, 0.f, 0.f};
#pragma unroll
        for (int ks = 0; ks < 4; ++ks) {
#pragma unroll
            for (int n = 0; n < 4; ++n) {
                acc[n] = __builtin_amdgcn_mfma_f32_16x16x32_bf16(
                    af[ks], bfrag[n][ks], acc[n], 0, 0, 0);
            }
        }
        // e for words 16m + 4g + r : reduce over units (4 n-tiles in-lane,
        // then 16 lanes of the group via butterfly)
#pragma unroll
        for (int r = 0; r < 4; ++r) {
            float p = 0.f;
#pragma unroll
            for (int n = 0; n < 4; ++n) {
                p = __builtin_fmaf(vwl[n], fast_tanh(acc[n][r] + gl[n]), p);
            }
            p += __shfl_xor(p, 1);
            p += __shfl_xor(p, 2);
            p += __shfl_xor(p, 4);
            p += __shfl_xor(p, 8);
            e[m][r] = p;
        }
    }

    // ---- softmax over the 64 words of this section ----
    float mx = e[0][0];
#pragma unroll
    for (int m = 0; m < 4; ++m)
#pragma unroll
        for (int r = 0; r < 4; ++r) mx = fmaxf(mx, e[m][r]);
    mx = fmaxf(mx, __shfl_xor(mx, 16));
    mx = fmaxf(mx, __shfl_xor(mx, 32));
    float sm = 0.f;
#pragma unroll
    for (int m = 0; m < 4; ++m)
#pragma unroll
        for (int r = 0; r < 4; ++r) {
            e[m][r] = __expf(e[m][r] - mx);
            sm += e[m][r];
        }
    sm += __shfl_xor(sm, 16);
    sm += __shfl_xor(sm, 32);
    const float inv = 1.0f / sm;

    if (li == 0) {
#pragma unroll
        for (int m = 0; m < 4; ++m)
#pragma unroll
            for (int r = 0; r < 4; ++r)
                alpha_s[wid][16 * m + 4 * g + r] = e[m][r] * inv;
    }
    __syncthreads();

    // ---- weighted-sum pooling (fp32 from global, L1/L2-hot) ----
    float o0 = 0.f, o1 = 0.f;
    const float* al = alpha_s[wid];
#pragma unroll 8
    for (int w = 0; w < SEC_; ++w) {
        const float aw = al[w];
        o0 = __builtin_fmaf(aw, secbase[w * D_ + l], o0);
        if (l < D_ - SEC_) o1 = __builtin_fmaf(aw, secbase[w * D_ + SEC_ + l], o1);
    }
    float* po = out + ((size_t)b * S_ + s) * D_;
    po[l] = o0;
    if (l < D_ - SEC_) po[SEC_ + l] = o1;
}

extern "C" void kernel_launch(void* const* d_in, const int* in_sizes, int n_in,
                              void* d_out, int out_size, void* d_ws, size_t ws_size,
                              hipStream_t stream) {
    const float* sent = (const float*)d_in[0];
    const float* uvec = (const float*)d_in[1];
    const float* vw   = (const float*)d_in[2];
    const float* wh   = (const float*)d_in[3];
    const float* wu   = (const float*)d_in[4];
    const float* bw   = (const float*)d_in[5];
    float* out = (float*)d_out;
    float* wup = (float*)d_ws;  // B_*U_ floats

    wu_proj_kernel<<<dim3(B_), dim3(64), 0, stream>>>(uvec, wu, bw, wup);
    attn_pool_mfma<<<dim3(B_ * 8), dim3(256), 0, stream>>>(sent, vw, wh, wup, out);
}

// Round 3
// 62.547 us; speedup vs baseline: 6.9760x; 2.1545x over previous
//
#include <hip/hip_runtime.h>
#include <hip/hip_bf16.h>

#define B_   256
#define T_   2048
#define D_   100
#define U_   50
#define S_   32
#define SEC_ 64

typedef __attribute__((ext_vector_type(8))) short short8;
typedef __attribute__((ext_vector_type(4))) float f32x4;

__device__ __forceinline__ float fast_tanh(float x) {
    // tanh(x) = 1 - 2/(1 + e^{2x}); safe at +-inf
    float e = __expf(2.0f * x);
    return 1.0f - 2.0f * __builtin_amdgcn_rcpf(1.0f + e);
}

__device__ __forceinline__ short f2bf(float f) {
    union { __hip_bfloat16 h; unsigned short u; } cv;
    cv.h = __float2bfloat16(f);  // RNE
    return (short)cv.u;
}

__device__ __forceinline__ short8 pack8(f32x4 a, f32x4 b) {
    short8 r;
    r[0] = f2bf(a[0]); r[1] = f2bf(a[1]); r[2] = f2bf(a[2]); r[3] = f2bf(a[3]);
    r[4] = f2bf(b[0]); r[5] = f2bf(b[1]); r[6] = f2bf(b[2]); r[7] = f2bf(b[3]);
    return r;
}

// wu_proj[b][u] = dot(user_vec[b], wu[u]) + bw[u]
__global__ __launch_bounds__(64) void wu_proj_kernel(
    const float* __restrict__ user_vec, const float* __restrict__ wu,
    const float* __restrict__ bw, float* __restrict__ wup) {
    int b = blockIdx.x;
    int u = threadIdx.x;
    if (u >= U_) return;
    const f32x4* uv4 = reinterpret_cast<const f32x4*>(user_vec + b * D_);
    const f32x4* wu4 = reinterpret_cast<const f32x4*>(wu + u * D_);
    float acc = 0.f;
#pragma unroll
    for (int c = 0; c < D_ / 4; ++c) {
        f32x4 a = uv4[c];
        f32x4 w = wu4[c];
        acc = __builtin_fmaf(a[0], w[0], acc);
        acc = __builtin_fmaf(a[1], w[1], acc);
        acc = __builtin_fmaf(a[2], w[2], acc);
        acc = __builtin_fmaf(a[3], w[3], acc);
    }
    wup[b * U_ + u] = acc + bw[u];
}

// Block = 4 waves, each wave owns one (b,s) section end-to-end.
// wh lives in LDS as pre-packed bf16 MFMA B-fragments; pooling is
// accumulated online (flash-style) from the in-register A f32 values.
__global__ __launch_bounds__(256, 2) void attn_pool_fused(
    const float* __restrict__ sent,     // [B, T, D]
    const float* __restrict__ vw,       // [U]
    const float* __restrict__ wh,       // [U, D]
    const float* __restrict__ wup_all,  // [B, U]
    float* __restrict__ out) {          // [B, S, D]
    __shared__ short8 whb[16][64];      // [(n*4+ks)][lane]  = 16 KB
    __shared__ float  poolbuf[4][128];  // per-wave store bounce = 2 KB

    const int tid = threadIdx.x;
    const int wid = tid >> 6;
    const int l   = tid & 63;
    const int g   = l >> 4;
    const int li  = l & 15;

    // ---- prologue: wh(f32, global) -> bf16 B-fragments in LDS ----
    // entry idx = ((n*4+ks)*4+g)*16+li ; lane part = idx & 63
#pragma unroll
    for (int j = 0; j < 4; ++j) {
        const int idx = tid + 256 * j;
        const int pli = idx & 15;
        const int pg  = (idx >> 4) & 3;
        const int pks = (idx >> 6) & 3;
        const int pn  = idx >> 8;
        const int u   = 16 * pn + pli;
        const bool uv = (u < U_);
        const int k0  = 32 * pks + 4 * pg;
        const bool v1 = uv && (k0 <= D_ - 4);        // chunk k0..k0+3
        const bool v2 = uv && (k0 + 16 <= D_ - 4);   // chunk k0+16..k0+19
        const float* rowp = wh + (uv ? u : 0) * D_;
        f32x4 a = *reinterpret_cast<const f32x4*>(rowp + (v1 ? k0 : 0));
        f32x4 b = *reinterpret_cast<const f32x4*>(rowp + (v2 ? k0 + 16 : 0));
        a *= (v1 ? 1.f : 0.f);
        b *= (v2 ? 1.f : 0.f);
        whb[idx >> 6][idx & 63] = pack8(a, b);
    }

    const int b  = blockIdx.x >> 3;
    const int s  = (blockIdx.x & 7) * 4 + wid;
    const float* secbase = sent + ((size_t)b * T_ + (size_t)s * SEC_) * D_;
    const float* wup = wup_all + b * U_;

    // per-lane vw / wu_proj slices (unit u = 16n + li)
    float vwl[4], gl[4];
#pragma unroll
    for (int n = 0; n < 4; ++n) {
        const int uu = 16 * n + li;
        const bool uv = (uu < U_);
        const int uc = uv ? uu : 0;
        const float rv = uv ? 1.f : 0.f;
        vwl[n] = vw[uc] * rv;
        gl[n]  = wup[uc] * rv;
    }
    __syncthreads();

    // ---- main: 4 m-tiles of 16 words; online-softmax pooling ----
    f32x4 pool[7];
#pragma unroll
    for (int j = 0; j < 7; ++j) pool[j] = (f32x4){0.f, 0.f, 0.f, 0.f};
    float rm = -1e30f, rs = 0.f;
    const float mg = (g == 0) ? 1.f : 0.f;  // ks=3 k-chunk valid only for g==0
    const int c0 = 4 * g;

#pragma unroll 2
    for (int m = 0; m < 4; ++m) {
        const float* row = secbase + (16 * m + li) * D_;
        f32x4 x[7];
        x[0] = *reinterpret_cast<const f32x4*>(row + c0);
        x[1] = *reinterpret_cast<const f32x4*>(row + c0 + 16);
        x[2] = *reinterpret_cast<const f32x4*>(row + c0 + 32);
        x[3] = *reinterpret_cast<const f32x4*>(row + c0 + 48);
        x[4] = *reinterpret_cast<const f32x4*>(row + c0 + 64);
        x[5] = *reinterpret_cast<const f32x4*>(row + c0 + 80);
        x[6] = *reinterpret_cast<const f32x4*>(row + 96);
        x[6] *= mg;

        short8 af[4];
        af[0] = pack8(x[0], x[1]);
        af[1] = pack8(x[2], x[3]);
        af[2] = pack8(x[4], x[5]);
        af[3] = pack8(x[6], (f32x4){0.f, 0.f, 0.f, 0.f});

        f32x4 acc[4];
#pragma unroll
        for (int n = 0; n < 4; ++n) acc[n] = (f32x4){0.f, 0.f, 0.f, 0.f};
#pragma unroll
        for (int ks = 0; ks < 4; ++ks) {
#pragma unroll
            for (int n = 0; n < 4; ++n) {
                acc[n] = __builtin_amdgcn_mfma_f32_16x16x32_bf16(
                    af[ks], whb[n * 4 + ks][l], acc[n], 0, 0, 0);
            }
        }

        // e for words 16m + 4g + r (replicated across li after butterfly)
        float p[4];
#pragma unroll
        for (int r = 0; r < 4; ++r) {
            float t = 0.f;
#pragma unroll
            for (int n = 0; n < 4; ++n)
                t = __builtin_fmaf(vwl[n], fast_tanh(acc[n][r] + gl[n]), t);
            t += __shfl_xor(t, 1);
            t += __shfl_xor(t, 2);
            t += __shfl_xor(t, 4);
            t += __shfl_xor(t, 8);
            p[r] = t;
        }

        // online softmax update (all quantities wave-replicated as needed)
        float tm = fmaxf(fmaxf(p[0], p[1]), fmaxf(p[2], p[3]));
        tm = fmaxf(tm, __shfl_xor(tm, 16));
        tm = fmaxf(tm, __shfl_xor(tm, 32));
        const float nm = fmaxf(rm, tm);
        const float sc = __expf(rm - nm);  // first iter: exp(-huge) = 0
#pragma unroll
        for (int r = 0; r < 4; ++r) p[r] = __expf(p[r] - nm);
        float ts = p[0] + p[1] + p[2] + p[3];
        ts += __shfl_xor(ts, 16);
        ts += __shfl_xor(ts, 32);
        rs = rs * sc + ts;
        rm = nm;

        // weight for THIS lane's A-rows (word 16m + li): lives in group li>>2, reg li&3
        const int src = (li >> 2) << 4;
        const float w0 = __shfl(p[0], src);
        const float w1 = __shfl(p[1], src);
        const float w2 = __shfl(p[2], src);
        const float w3 = __shfl(p[3], src);
        const float wa = (li & 1) ? w1 : w0;
        const float wb = (li & 1) ? w3 : w2;
        const float wgt = (li & 2) ? wb : wa;

#pragma unroll
        for (int j = 0; j < 7; ++j) {
            pool[j] = pool[j] * sc + x[j] * wgt;
        }
    }

    // ---- reduce pooling partials over the 16 rows (li lanes) ----
#pragma unroll
    for (int j = 0; j < 7; ++j) {
#pragma unroll
        for (int c = 0; c < 4; ++c) {
            float v = pool[j][c];
            v += __shfl_xor(v, 1);
            v += __shfl_xor(v, 2);
            v += __shfl_xor(v, 4);
            v += __shfl_xor(v, 8);
            pool[j][c] = v;
        }
    }
    const float inv = 1.0f / rs;

    // ---- store via tiny per-wave LDS bounce (coalesced global store) ----
    if (li == 0) {
#pragma unroll
        for (int j = 0; j < 6; ++j) {
#pragma unroll
            for (int c = 0; c < 4; ++c) {
                const int k = 32 * (j >> 1) + 16 * (j & 1) + 4 * g + c;
                poolbuf[wid][k] = pool[j][c];
            }
        }
        if (g == 0) {
#pragma unroll
            for (int c = 0; c < 4; ++c) poolbuf[wid][96 + c] = pool[6][c];
        }
    }
    asm volatile("s_waitcnt lgkmcnt(0)" ::: "memory");

    float* po = out + ((size_t)b * S_ + s) * D_;
    po[l] = poolbuf[wid][l] * inv;
    if (l < D_ - SEC_) po[SEC_ + l] = poolbuf[wid][SEC_ + l] * inv;
}

extern "C" void kernel_launch(void* const* d_in, const int* in_sizes, int n_in,
                              void* d_out, int out_size, void* d_ws, size_t ws_size,
                              hipStream_t stream) {
    const float* sent = (const float*)d_in[0];
    const float* uvec = (const float*)d_in[1];
    const float* vw   = (const float*)d_in[2];
    const float* wh   = (const float*)d_in[3];
    const float* wu   = (const float*)d_in[4];
    const float* bw   = (const float*)d_in[5];
    float* out = (float*)d_out;
    float* wup = (float*)d_ws;  // B_*U_ floats

    wu_proj_kernel<<<dim3(B_), dim3(64), 0, stream>>>(uvec, wu, bw, wup);
    attn_pool_fused<<<dim3(B_ * S_ / 4), dim3(256), 0, stream>>>(sent, vw, wh, wup, out);
}